// Round 1
// baseline (652.086 us; speedup 1.0000x reference)
//
#include <hip/hip_runtime.h>
#include <stdint.h>

#define BATCH 4096
#define DIN 1024
#define DOUT 1024
#define NC 11          // GRID_SIZE + SPLINE_ORDER
#define KD 12288       // DIN * (1 + NC)
#define NKNOTS 15      // GRID_SIZE + 2*SPLINE_ORDER + 1

typedef __bf16 bf16x8 __attribute__((ext_vector_type(8)));
typedef float f32x4 __attribute__((ext_vector_type(4)));

__device__ __forceinline__ unsigned short f2bf(float f) {
    unsigned int u = __float_as_uint(f);
    unsigned int r = (u + 0x7FFFu + ((u >> 16) & 1u)) >> 16;
    return (unsigned short)r;
}

// ---------------------------------------------------------------------------
// Build A[b, :] = [ silu(x[b,:]) (1024) | bsplines(silu(x[b,:])) (1024*11) ] in bf16
// One block = 256 consecutive i of one row b.
// ---------------------------------------------------------------------------
__global__ __launch_bounds__(256) void build_A(
    const float* __restrict__ x, const float* __restrict__ grid,
    unsigned short* __restrict__ A) {
    __shared__ __align__(16) unsigned short lbs[256 * NC];
    const int tid = threadIdx.x;
    const int b  = blockIdx.x >> 2;
    const int i0 = (blockIdx.x & 3) * 256;
    const int i  = i0 + tid;

    float g[NKNOTS];
#pragma unroll
    for (int j = 0; j < NKNOTS; ++j) g[j] = grid[j];

    const float xv = x[(size_t)b * DIN + i];
    const float s  = xv / (1.f + __expf(-xv));   // silu

    // Cox-de Boor, order 0..3. Uniform grid: denominators are exactly k*h.
    float bs[14];
#pragma unroll
    for (int c = 0; c < 14; ++c) bs[c] = (s >= g[c] && s < g[c + 1]) ? 1.f : 0.f;
#pragma unroll
    for (int k = 1; k <= 3; ++k) {
        const float inv = (k == 1) ? 4.f : (k == 2) ? 2.f : (4.f / 3.f);
#pragma unroll
        for (int c = 0; c < 14 - k; ++c) {
            float left  = (s - g[c]) * inv;
            float right = (g[c + k + 1] - s) * inv;
            bs[c] = left * bs[c] + right * bs[c + 1];
        }
    }

    A[(size_t)b * KD + i] = f2bf(s);
#pragma unroll
    for (int c = 0; c < NC; ++c) lbs[tid * NC + c] = f2bf(bs[c]);
    __syncthreads();

    // cooperative coalesced copy-out: 256*11*2B = 5632B = 352 uint4
    const uint4* src = (const uint4*)lbs;
    uint4* dst = (uint4*)(A + (size_t)b * KD + DIN + (size_t)i0 * NC);
    for (int j = tid; j < 352; j += 256) dst[j] = src[j];
}

// ---------------------------------------------------------------------------
// Build W[o, :] = [ base_w[o,:] | spline_w[o,:,:]*scaler[o,:] ] in bf16
// ---------------------------------------------------------------------------
__global__ __launch_bounds__(256) void build_W(
    const float* __restrict__ base_w, const float* __restrict__ spline_w,
    const float* __restrict__ scaler, unsigned short* __restrict__ W) {
    __shared__ __align__(16) unsigned short lw[256 * NC];
    const int tid = threadIdx.x;
    const int o  = blockIdx.x >> 2;
    const int i0 = (blockIdx.x & 3) * 256;
    const int i  = i0 + tid;
    const size_t oi = (size_t)o * DIN + i;

    const float sc = scaler[oi];
    W[(size_t)o * KD + i] = f2bf(base_w[oi]);
    const float* sw = spline_w + oi * NC;
#pragma unroll
    for (int c = 0; c < NC; ++c) lw[tid * NC + c] = f2bf(sw[c] * sc);
    __syncthreads();

    const uint4* src = (const uint4*)lw;
    uint4* dst = (uint4*)(W + (size_t)o * KD + DIN + (size_t)i0 * NC);
    for (int j = tid; j < 352; j += 256) dst[j] = src[j];
}

// ---------------------------------------------------------------------------
// GEMM: C[4096,1024] = A[4096,12288](bf16) @ W[1024,12288]^T(bf16), f32 out.
// 128x128 tile, BK=64, 512 threads (8 waves, 2x4), 2-phase LDS double-buffer,
// global_load_lds width-16 staging. One K-step: 12 ds_read_b128 + 16 MFMA/wave.
// ---------------------------------------------------------------------------
#define BM 128
#define BN 128
#define BK 64
#define KTILES (KD / BK)   // 192

__global__ __launch_bounds__(512) void gemm_kan(
    const unsigned short* __restrict__ A,
    const unsigned short* __restrict__ W,
    float* __restrict__ C) {
    __shared__ unsigned short As[2][BM * BK];   // 2 x 16KB
    __shared__ unsigned short Bs[2][BN * BK];   // 2 x 16KB

    const int tid  = threadIdx.x;
    const int wave = tid >> 6;
    const int lane = tid & 63;
    const int m0 = (blockIdx.x >> 3) * BM;
    const int n0 = (blockIdx.x & 7) * BN;       // bid%8 == XCD: W panel stays in L2
    const int wm = wave >> 2;                   // 0..1
    const int wn = wave & 3;                    // 0..3

    // staging: 1KB per global_load_lds = 8 rows x 64 cols(bf16)
    const int srow = lane >> 3;                 // 0..7 row within chunk
    const int scol = (lane & 7) * 8;            // element col within BK

    f32x4 acc[4][2];
#pragma unroll
    for (int a = 0; a < 4; ++a)
#pragma unroll
        for (int b = 0; b < 2; ++b) acc[a][b] = (f32x4){0.f, 0.f, 0.f, 0.f};

    auto stage = [&](int buf, int kt) {
        const int kk = kt * BK + scol;
#pragma unroll
        for (int c = 0; c < 2; ++c) {
            const int chunk = wave * 2 + c;     // 0..15
            const unsigned short* ga = A + (size_t)(m0 + chunk * 8 + srow) * KD + kk;
            __builtin_amdgcn_global_load_lds(
                (const __attribute__((address_space(1))) unsigned int*)ga,
                (__attribute__((address_space(3))) unsigned int*)&As[buf][chunk * 512],
                16, 0, 0);
            const unsigned short* gb = W + (size_t)(n0 + chunk * 8 + srow) * KD + kk;
            __builtin_amdgcn_global_load_lds(
                (const __attribute__((address_space(1))) unsigned int*)gb,
                (__attribute__((address_space(3))) unsigned int*)&Bs[buf][chunk * 512],
                16, 0, 0);
        }
    };

    stage(0, 0);
    __syncthreads();   // vmcnt(0) drain: tile 0 resident

    const int arow = wm * 64 + (lane & 15);
    const int brow = wn * 32 + (lane & 15);
    const int koff = (lane >> 4) * 8;

    for (int kt = 0; kt < KTILES; ++kt) {
        const int cur = kt & 1;
        if (kt + 1 < KTILES) stage(cur ^ 1, kt + 1);   // prefetch next tile
#pragma unroll
        for (int ks = 0; ks < 2; ++ks) {
            bf16x8 af[4], bfr[2];
#pragma unroll
            for (int fm = 0; fm < 4; ++fm)
                af[fm] = *(const bf16x8*)&As[cur][(arow + fm * 16) * BK + ks * 32 + koff];
#pragma unroll
            for (int fn = 0; fn < 2; ++fn)
                bfr[fn] = *(const bf16x8*)&Bs[cur][(brow + fn * 16) * BK + ks * 32 + koff];
#pragma unroll
            for (int fm = 0; fm < 4; ++fm)
#pragma unroll
                for (int fn = 0; fn < 2; ++fn)
                    acc[fm][fn] = __builtin_amdgcn_mfma_f32_16x16x32_bf16(
                        af[fm], bfr[fn], acc[fm][fn], 0, 0, 0);
        }
        __syncthreads();   // drains vmcnt(0) for prefetched tile + guards buffer reuse
    }

    // epilogue: C/D layout col=lane&15, row=(lane>>4)*4+reg
    const int crow = (lane >> 4) * 4;
    const int ccol = lane & 15;
#pragma unroll
    for (int fm = 0; fm < 4; ++fm)
#pragma unroll
        for (int fn = 0; fn < 2; ++fn) {
            const int row = m0 + wm * 64 + fm * 16 + crow;
            const int col = n0 + wn * 32 + fn * 16 + ccol;
#pragma unroll
            for (int r = 0; r < 4; ++r)
                C[(size_t)(row + r) * DOUT + col] = acc[fm][fn][r];
        }
}

// ---------------------------------------------------------------------------
extern "C" void kernel_launch(void* const* d_in, const int* in_sizes, int n_in,
                              void* d_out, int out_size, void* d_ws, size_t ws_size,
                              hipStream_t stream) {
    const float* x        = (const float*)d_in[0];
    const float* base_w   = (const float*)d_in[1];
    const float* spline_w = (const float*)d_in[2];
    const float* scaler   = (const float*)d_in[3];
    const float* grid     = (const float*)d_in[4];
    float* out = (float*)d_out;

    char* ws = (char*)d_ws;
    unsigned short* Abf = (unsigned short*)ws;                         // 100,663,296 B
    unsigned short* Wbf = (unsigned short*)(ws + 100663296);           //  25,165,824 B
    float* xtmp = (float*)(ws + 100663296 + 25165824);                 //  16,777,216 B

    for (int layer = 0; layer < 2; ++layer) {
        const float* xin = (layer == 0) ? x : xtmp;
        float* xout      = (layer == 0) ? xtmp : out;
        build_W<<<4096, 256, 0, stream>>>(base_w + (size_t)layer * DOUT * DIN,
                                          spline_w + (size_t)layer * DOUT * DIN * NC,
                                          scaler + (size_t)layer * DOUT * DIN, Wbf);
        build_A<<<16384, 256, 0, stream>>>(xin, grid, Abf);
        gemm_kan<<<256, 512, 0, stream>>>(Abf, Wbf, xout);
    }
}

// Round 2
// 482.407 us; speedup vs baseline: 1.3517x; 1.3517x over previous
//
#include <hip/hip_runtime.h>
#include <stdint.h>

#define BATCH 4096
#define DIN 1024
#define DOUT 1024
#define NC 11          // GRID_SIZE + SPLINE_ORDER
#define KD 12288       // DIN * (1 + NC)
#define NKNOTS 15      // GRID_SIZE + 2*SPLINE_ORDER + 1

typedef __bf16 bf16x8 __attribute__((ext_vector_type(8)));
typedef float f32x4 __attribute__((ext_vector_type(4)));

__device__ __forceinline__ unsigned short f2bf(float f) {
    unsigned int u = __float_as_uint(f);
    unsigned int r = (u + 0x7FFFu + ((u >> 16) & 1u)) >> 16;
    return (unsigned short)r;
}

// ---------------------------------------------------------------------------
// Build A[b, :] = [ silu(x[b,:]) (1024) | bsplines(silu(x[b,:])) (1024*11) ] in bf16
// ---------------------------------------------------------------------------
__global__ __launch_bounds__(256) void build_A(
    const float* __restrict__ x, const float* __restrict__ grid,
    unsigned short* __restrict__ A) {
    __shared__ __align__(16) unsigned short lbs[256 * NC];
    const int tid = threadIdx.x;
    const int b  = blockIdx.x >> 2;
    const int i0 = (blockIdx.x & 3) * 256;
    const int i  = i0 + tid;

    float g[NKNOTS];
#pragma unroll
    for (int j = 0; j < NKNOTS; ++j) g[j] = grid[j];

    const float xv = x[(size_t)b * DIN + i];
    const float s  = xv / (1.f + __expf(-xv));   // silu

    float bs[14];
#pragma unroll
    for (int c = 0; c < 14; ++c) bs[c] = (s >= g[c] && s < g[c + 1]) ? 1.f : 0.f;
#pragma unroll
    for (int k = 1; k <= 3; ++k) {
        const float inv = (k == 1) ? 4.f : (k == 2) ? 2.f : (4.f / 3.f);
#pragma unroll
        for (int c = 0; c < 14 - k; ++c) {
            float left  = (s - g[c]) * inv;
            float right = (g[c + k + 1] - s) * inv;
            bs[c] = left * bs[c] + right * bs[c + 1];
        }
    }

    A[(size_t)b * KD + i] = f2bf(s);
#pragma unroll
    for (int c = 0; c < NC; ++c) lbs[tid * NC + c] = f2bf(bs[c]);
    __syncthreads();

    const uint4* src = (const uint4*)lbs;
    uint4* dst = (uint4*)(A + (size_t)b * KD + DIN + (size_t)i0 * NC);
    for (int j = tid; j < 352; j += 256) dst[j] = src[j];
}

// ---------------------------------------------------------------------------
// Build W[o, :] = [ base_w[o,:] | spline_w[o,:,:]*scaler[o,:] ] in bf16
// ---------------------------------------------------------------------------
__global__ __launch_bounds__(256) void build_W(
    const float* __restrict__ base_w, const float* __restrict__ spline_w,
    const float* __restrict__ scaler, unsigned short* __restrict__ W) {
    __shared__ __align__(16) unsigned short lw[256 * NC];
    const int tid = threadIdx.x;
    const int o  = blockIdx.x >> 2;
    const int i0 = (blockIdx.x & 3) * 256;
    const int i  = i0 + tid;
    const size_t oi = (size_t)o * DIN + i;

    const float sc = scaler[oi];
    W[(size_t)o * KD + i] = f2bf(base_w[oi]);
    const float* sw = spline_w + oi * NC;
#pragma unroll
    for (int c = 0; c < NC; ++c) lw[tid * NC + c] = f2bf(sw[c] * sc);
    __syncthreads();

    const uint4* src = (const uint4*)lw;
    uint4* dst = (uint4*)(W + (size_t)o * KD + DIN + (size_t)i0 * NC);
    for (int j = tid; j < 352; j += 256) dst[j] = src[j];
}

// ---------------------------------------------------------------------------
// GEMM: C[4096,1024] = A[4096,12288](bf16) @ W[1024,12288]^T(bf16), f32 out.
// 128x128 tile, BK=64, 512 threads (8 waves, 2x4).
// 4-deep LDS ring, counted vmcnt(8) (never drain to 0 in main loop),
// raw s_barrier (1/K-step), T2 XOR-swizzle via pre-swizzled global source.
// ---------------------------------------------------------------------------
#define BM 128
#define BN 128
#define BK 64
#define KTILES (KD / BK)   // 192
#define DEPTH 4

__global__ __launch_bounds__(512) void gemm_kan(
    const unsigned short* __restrict__ A,
    const unsigned short* __restrict__ W,
    float* __restrict__ C) {
    __shared__ unsigned short As[DEPTH][BM * BK];   // 4 x 16KB
    __shared__ unsigned short Bs[DEPTH][BN * BK];   // 4 x 16KB  (128KB total)

    const int tid  = threadIdx.x;
    const int wave = tid >> 6;
    const int lane = tid & 63;
    const int m0 = (blockIdx.x >> 3) * BM;
    const int n0 = (blockIdx.x & 7) * BN;       // bid%8 == XCD: W panel stays in L2
    const int wm = wave >> 2;                   // 0..1
    const int wn = wave & 3;                    // 0..3

    // staging: linear LDS dest (lane*16B); global source col pre-swizzled so that
    // LDS[row][c'] holds global col c = c' ^ ((row&7)<<4)  (T2, rule #21)
    const int srow = lane >> 3;                           // 0..7 row within 8-row chunk
    const int scol = 8 * ((lane & 7) ^ (lane >> 3));      // pre-swizzled elem col in BK

    f32x4 acc[4][2];
#pragma unroll
    for (int a = 0; a < 4; ++a)
#pragma unroll
        for (int b = 0; b < 2; ++b) acc[a][b] = (f32x4){0.f, 0.f, 0.f, 0.f};

    auto stage = [&](int kt) {
        const int buf = kt & (DEPTH - 1);
        const int kk = kt * BK + scol;
#pragma unroll
        for (int c = 0; c < 2; ++c) {
            const int chunk = wave * 2 + c;     // 0..15
            const unsigned short* ga = A + (size_t)(m0 + chunk * 8 + srow) * KD + kk;
            __builtin_amdgcn_global_load_lds(
                (const __attribute__((address_space(1))) unsigned int*)ga,
                (__attribute__((address_space(3))) unsigned int*)&As[buf][chunk * 512],
                16, 0, 0);
            const unsigned short* gb = W + (size_t)(n0 + chunk * 8 + srow) * KD + kk;
            __builtin_amdgcn_global_load_lds(
                (const __attribute__((address_space(1))) unsigned int*)gb,
                (__attribute__((address_space(3))) unsigned int*)&Bs[buf][chunk * 512],
                16, 0, 0);
        }
    };

    // prologue: fill 3 of 4 ring slots (12 loads/wave in flight)
    stage(0);
    stage(1);
    stage(2);

    const int arow = wm * 64 + (lane & 15);
    const int brow = wn * 32 + (lane & 15);
    const int xr   = lane & 7;        // row&7 for every fragment row this lane reads
    const int kcol = lane >> 4;       // 0..3: which 8-elem k-slot

    for (int kt = 0; kt < KTILES; ++kt) {
        const int cur = kt & (DEPTH - 1);
        // tile kt was issued 3 iterations ago; leave kt+1/kt+2's 8 loads in flight
        if (kt < KTILES - 2)       asm volatile("s_waitcnt vmcnt(8)" ::: "memory");
        else if (kt == KTILES - 2) asm volatile("s_waitcnt vmcnt(4)" ::: "memory");
        else                       asm volatile("s_waitcnt vmcnt(0)" ::: "memory");
        __builtin_amdgcn_sched_barrier(0);
        __builtin_amdgcn_s_barrier();   // all waves: tile kt resident, tile kt-1 consumed
        __builtin_amdgcn_sched_barrier(0);

        if (kt + 3 < KTILES) stage(kt + 3);   // into ring slot (kt+3)&3 == (kt-1)&3

        __builtin_amdgcn_s_setprio(1);
#pragma unroll
        for (int ks = 0; ks < 2; ++ks) {
            const int slot = (((ks * 4 + kcol) ^ xr)) * 8;   // swizzled k-slot (elems)
            bf16x8 af[4], bfr[2];
#pragma unroll
            for (int fm = 0; fm < 4; ++fm)
                af[fm] = *(const bf16x8*)&As[cur][(arow + fm * 16) * BK + slot];
#pragma unroll
            for (int fn = 0; fn < 2; ++fn)
                bfr[fn] = *(const bf16x8*)&Bs[cur][(brow + fn * 16) * BK + slot];
#pragma unroll
            for (int fm = 0; fm < 4; ++fm)
#pragma unroll
                for (int fn = 0; fn < 2; ++fn)
                    acc[fm][fn] = __builtin_amdgcn_mfma_f32_16x16x32_bf16(
                        af[fm], bfr[fn], acc[fm][fn], 0, 0, 0);
        }
        __builtin_amdgcn_s_setprio(0);
    }

    // epilogue: C/D layout col=lane&15, row=(lane>>4)*4+reg
    const int crow = (lane >> 4) * 4;
    const int ccol = lane & 15;
#pragma unroll
    for (int fm = 0; fm < 4; ++fm)
#pragma unroll
        for (int fn = 0; fn < 2; ++fn) {
            const int row = m0 + wm * 64 + fm * 16 + crow;
            const int col = n0 + wn * 32 + fn * 16 + ccol;
#pragma unroll
            for (int r = 0; r < 4; ++r)
                C[(size_t)(row + r) * DOUT + col] = acc[fm][fn][r];
        }
}

// ---------------------------------------------------------------------------
extern "C" void kernel_launch(void* const* d_in, const int* in_sizes, int n_in,
                              void* d_out, int out_size, void* d_ws, size_t ws_size,
                              hipStream_t stream) {
    const float* x        = (const float*)d_in[0];
    const float* base_w   = (const float*)d_in[1];
    const float* spline_w = (const float*)d_in[2];
    const float* scaler   = (const float*)d_in[3];
    const float* grid     = (const float*)d_in[4];
    float* out = (float*)d_out;

    char* ws = (char*)d_ws;
    unsigned short* Abf = (unsigned short*)ws;                         // 100,663,296 B
    unsigned short* Wbf = (unsigned short*)(ws + 100663296);           //  25,165,824 B
    float* xtmp = (float*)(ws + 100663296 + 25165824);                 //  16,777,216 B

    for (int layer = 0; layer < 2; ++layer) {
        const float* xin = (layer == 0) ? x : xtmp;
        float* xout      = (layer == 0) ? xtmp : out;
        build_W<<<4096, 256, 0, stream>>>(base_w + (size_t)layer * DOUT * DIN,
                                          spline_w + (size_t)layer * DOUT * DIN * NC,
                                          scaler + (size_t)layer * DOUT * DIN, Wbf);
        build_A<<<16384, 256, 0, stream>>>(xin, grid, Abf);
        gemm_kan<<<256, 512, 0, stream>>>(Abf, Wbf, xout);
    }
}